// Round 2
// baseline (679.353 us; speedup 1.0000x reference)
//
#include <hip/hip_runtime.h>

#define HW (512*512)
#define NB 8
#define NC 14
#define NPIX (NB*HW)
#define DELTA_F 0.7f
#define FUS_F 0.01f
#define NWAVES 4

// ws layout (4-byte units): [0..195] A (float), [196..391] cm (uint),
// [392] ce_sum (float), [393] bl_sum (float)

__global__ __launch_bounds__(256, 4) void main_pass(
    const float* __restrict__ y_pred, const float* __restrict__ weight,
    const int* __restrict__ y_true, const int* __restrict__ backlabel,
    float* __restrict__ gA, unsigned* __restrict__ gcm, float* __restrict__ gsums)
{
    // per-wave private slices: no inter-wave LDS atomic contention
    __shared__ float    sA[NWAVES][NC * NC];
    __shared__ unsigned sCM[NWAVES][NC * NC];
    __shared__ float    sW[NC];

    const int tid = threadIdx.x;
    const int wv  = tid >> 6;
    for (int j = tid; j < NWAVES * NC * NC; j += blockDim.x) {
        (&sA[0][0])[j] = 0.0f; (&sCM[0][0])[j] = 0u;
    }
    if (tid < NC) sW[tid] = weight[tid];
    __syncthreads();

    float ceAcc = 0.0f, blAcc = 0.0f;

    // exact mapping: 4096 blocks x 256 threads x 2 pixels = 2,097,152 pixels
    const int q   = blockIdx.x * 256 + tid;      // pixel-pair index
    const int b   = q / (HW / 2);
    const int hw2 = q - b * (HW / 2);

    float x[NC][2];
    #pragma unroll
    for (int c = 0; c < NC; ++c) {
        const float2 v = *reinterpret_cast<const float2*>(
            y_pred + (size_t)(b * NC + c) * HW + (size_t)hw2 * 2);
        x[c][0] = v.x; x[c][1] = v.y;
    }
    const int pix = b * HW + hw2 * 2;
    const int2 t2  = *reinterpret_cast<const int2*>(y_true + pix);
    const int2 bb2 = *reinterpret_cast<const int2*>(backlabel + pix);
    const int ts[2] = { t2.x, t2.y };
    const int bs[2] = { bb2.x, bb2.y };

    #pragma unroll
    for (int j = 0; j < 2; ++j) {
        int t = ts[j];
        t = (t < 0) ? 0 : ((t >= NC) ? (NC - 1) : t);   // safety clamp
        const int bb = bs[j];
        const float bl = (bb == 0) ? 0.4f : (float)bb;

        // max + argmax (first-occurrence via strict >) + x[t] via static-index select
        float m  = x[0][j];
        int   am = 0;
        float xt = x[0][j];
        #pragma unroll
        for (int c = 1; c < NC; ++c) {
            const float xc = x[c][j];
            if (xc > m) { m = xc; am = c; }
            xt = (c == t) ? xc : xt;
        }

        float e[NC];
        float s = 0.0f;
        #pragma unroll
        for (int c = 0; c < NC; ++c) { e[c] = __expf(x[c][j] - m); s += e[c]; }
        const float inv = 1.0f / s;
        const float lse = __logf(s);

        const float nll = -(xt - m - lse);
        ceAcc += sW[t] * nll * bl;
        blAcc += bl;

        atomicAdd(&sCM[wv][t * NC + am], 1u);
        const float blinv = bl * inv;
        #pragma unroll
        for (int c = 0; c < NC; ++c)
            unsafeAtomicAdd(&sA[wv][t * NC + c], blinv * e[c]);
    }
    __syncthreads();

    // flush: sum the 4 per-wave slices, one global atomic set per block
    for (int j = tid; j < NC * NC; j += blockDim.x) {
        const float a = sA[0][j] + sA[1][j] + sA[2][j] + sA[3][j];
        if (a != 0.0f) unsafeAtomicAdd(&gA[j], a);
        const unsigned cmv = sCM[0][j] + sCM[1][j] + sCM[2][j] + sCM[3][j];
        if (cmv) atomicAdd(&gcm[j], cmv);
    }

    // wave-reduce scalar partials, one atomic per wave
    #pragma unroll
    for (int o = 32; o > 0; o >>= 1) {
        ceAcc += __shfl_down(ceAcc, o, 64);
        blAcc += __shfl_down(blAcc, o, 64);
    }
    if ((tid & 63) == 0) {
        unsafeAtomicAdd(&gsums[0], ceAcc);
        unsafeAtomicAdd(&gsums[1], blAcc);
    }
}

__global__ __launch_bounds__(256) void finalize_pass(
    const float* __restrict__ gA, const unsigned* __restrict__ gcm,
    const float* __restrict__ gsums, const float* __restrict__ wei_confus,
    float* __restrict__ out)
{
    __shared__ float cinv[NC];
    __shared__ float red[4];
    const int tid = threadIdx.x;

    if (tid < NC) {
        float col = 0.0f;
        for (int r = 0; r < NC; ++r) col += (float)gcm[r * NC + tid];
        cinv[tid] = (col == 0.0f) ? 1.0f : (1.0f / col);
    }
    __syncthreads();

    float part = 0.0f;
    for (int idx = tid; idx < NC * NC; idx += blockDim.x) {
        const int t = idx / NC;
        const int c = idx - t * NC;
        // wc[c][t] = (wei_confus[c][t] + 0.01 * cm[c][t] / col[t]) / 1.01
        const float wc = (wei_confus[c * NC + t]
                          + FUS_F * (float)gcm[c * NC + t] * cinv[t]) * (1.0f / (1.0f + FUS_F));
        part += gA[idx] * wc;
    }
    #pragma unroll
    for (int o = 32; o > 0; o >>= 1) part += __shfl_down(part, o, 64);
    if ((tid & 63) == 0) red[tid >> 6] = part;
    __syncthreads();

    if (tid == 0) {
        const float tot = red[0] + red[1] + red[2] + red[3];
        const float ce  = gsums[0];
        const float bls = gsums[1];
        out[0] = (bls * (1.0f / NC) - tot * (1.0f / NC) + DELTA_F * ce) * (1.0f / (float)NPIX);
    }
}

extern "C" void kernel_launch(void* const* d_in, const int* in_sizes, int n_in,
                              void* d_out, int out_size, void* d_ws, size_t ws_size,
                              hipStream_t stream) {
    const float* y_pred     = (const float*)d_in[0];
    const float* wei_confus = (const float*)d_in[1];
    const float* weight     = (const float*)d_in[2];
    const int*   y_true     = (const int*)d_in[3];
    const int*   backlabel  = (const int*)d_in[4];

    float*    gA    = (float*)d_ws;
    unsigned* gcm   = (unsigned*)((char*)d_ws + 196 * 4);
    float*    gsums = (float*)((char*)d_ws + 392 * 4);

    hipMemsetAsync(d_ws, 0, 394 * 4, stream);

    main_pass<<<NPIX / 512, 256, 0, stream>>>(y_pred, weight, y_true, backlabel, gA, gcm, gsums);
    finalize_pass<<<1, 256, 0, stream>>>(gA, gcm, gsums, wei_confus, (float*)d_out);
}

// Round 3
// 303.913 us; speedup vs baseline: 2.2354x; 2.2354x over previous
//
#include <hip/hip_runtime.h>

#define HW (512*512)           // 2^18
#define NB 8
#define NC 14
#define NPIX (NB*HW)
#define DELTA_F 0.7f
#define FUS_F 0.01f
#define NWAVES 4
#define NPART 8
#define NBLOCKS 2048
#define NTHREADS (NBLOCKS*256)
#define ITERS (NPIX/NTHREADS)  // 4

// ws layout (bytes):
//   [0      .. 6272)  gA   : float [NPART][196]
//   [6272   .. 12544) gcm  : uint  [NPART][196]
//   [12544  .. 12608) gsums: float [NPART][2]

#define REPEAT13(OP) OP(1) OP(2) OP(3) OP(4) OP(5) OP(6) OP(7) OP(8) OP(9) OP(10) OP(11) OP(12) OP(13)
#define REPEAT14(OP) OP(0) REPEAT13(OP)

__global__ __launch_bounds__(256, 8) void main_pass(
    const float* __restrict__ y_pred, const float* __restrict__ weight,
    const int* __restrict__ y_true, const int* __restrict__ backlabel,
    float* __restrict__ gA, unsigned* __restrict__ gcm, float* __restrict__ gsums)
{
    __shared__ float    sA[NWAVES][NC * NC];
    __shared__ unsigned sCM[NWAVES][NC * NC];
    __shared__ float    sW[NC];
    __shared__ float    sCe[NWAVES], sBl[NWAVES];

    const int tid = threadIdx.x;
    const int wv  = tid >> 6;
    for (int j = tid; j < NWAVES * NC * NC; j += 256) {
        (&sA[0][0])[j] = 0.0f; (&sCM[0][0])[j] = 0u;
    }
    if (tid < NC) sW[tid] = weight[tid];
    __syncthreads();

    float ceAcc = 0.0f, blAcc = 0.0f;
    const int gid = blockIdx.x * 256 + tid;

    #pragma unroll 1
    for (int i = 0; i < ITERS; ++i) {
        const int q  = gid + i * NTHREADS;
        const int b  = q >> 18;            // q / HW
        const int hw = q & (HW - 1);       // q % HW
        const float* px = y_pred + (((size_t)b * NC) << 18) + hw;

        // 14 named scalar loads — nothing indexable, nothing spillable
        #define LOADC(c) float x##c = px[(size_t)(c) << 18];
        REPEAT14(LOADC)
        #undef LOADC

        int t = y_true[q];
        t = (t < 0) ? 0 : ((t >= NC) ? (NC - 1) : t);
        const int bb = backlabel[q];
        const float bl = (bb == 0) ? 0.4f : (float)bb;

        // max + argmax (first occurrence via strict >)
        float m = x0; int am = 0;
        #define AMAX(c) if (x##c > m) { m = x##c; am = (c); }
        REPEAT13(AMAX)
        #undef AMAX

        // x[t] via cndmask chain
        float xt = x0;
        #define SELT(c) xt = (t == (c)) ? x##c : xt;
        REPEAT13(SELT)
        #undef SELT

        // exp in place + sum
        float s = 0.0f;
        #define EXPC(c) x##c = __expf(x##c - m); s += x##c;
        REPEAT14(EXPC)
        #undef EXPC

        const float inv = 1.0f / s;
        const float lse = __logf(s);

        ceAcc += sW[t] * (m + lse - xt) * bl;   // nll = -(x_t - m - lse)
        blAcc += bl;

        atomicAdd(&sCM[wv][t * NC + am], 1u);
        const float bi = bl * inv;
        float* row = &sA[wv][t * NC];
        #define ACCC(c) unsafeAtomicAdd(&row[(c)], bi * x##c);
        REPEAT14(ACCC)
        #undef ACCC
    }

    // wave-reduce scalars
    #pragma unroll
    for (int o = 32; o > 0; o >>= 1) {
        ceAcc += __shfl_down(ceAcc, o, 64);
        blAcc += __shfl_down(blAcc, o, 64);
    }
    if ((tid & 63) == 0) { sCe[wv] = ceAcc; sBl[wv] = blAcc; }
    __syncthreads();

    // flush block sums into one of NPART partitions (contention /8)
    const int part = blockIdx.x & (NPART - 1);
    if (tid < NC * NC) {
        const float a = sA[0][tid] + sA[1][tid] + sA[2][tid] + sA[3][tid];
        unsafeAtomicAdd(&gA[part * NC * NC + tid], a);
        const unsigned cmv = sCM[0][tid] + sCM[1][tid] + sCM[2][tid] + sCM[3][tid];
        if (cmv) atomicAdd(&gcm[part * NC * NC + tid], cmv);
    }
    if (tid == 0)
        unsafeAtomicAdd(&gsums[part * 2 + 0], sCe[0] + sCe[1] + sCe[2] + sCe[3]);
    if (tid == 1)
        unsafeAtomicAdd(&gsums[part * 2 + 1], sBl[0] + sBl[1] + sBl[2] + sBl[3]);
}

__global__ __launch_bounds__(256) void finalize_pass(
    const float* __restrict__ gA, const unsigned* __restrict__ gcm,
    const float* __restrict__ gsums, const float* __restrict__ wei_confus,
    float* __restrict__ out)
{
    __shared__ float sAt[NC * NC];
    __shared__ float sCmt[NC * NC];
    __shared__ float cinv[NC];
    __shared__ float red[4];
    const int tid = threadIdx.x;

    if (tid < NC * NC) {
        float a = 0.0f; unsigned cmv = 0u;
        for (int p = 0; p < NPART; ++p) {
            a   += gA[p * NC * NC + tid];
            cmv += gcm[p * NC * NC + tid];
        }
        sAt[tid] = a; sCmt[tid] = (float)cmv;
    }
    __syncthreads();

    if (tid < NC) {
        float col = 0.0f;
        for (int r = 0; r < NC; ++r) col += sCmt[r * NC + tid];
        cinv[tid] = (col == 0.0f) ? 1.0f : (1.0f / col);
    }
    __syncthreads();

    float partv = 0.0f;
    if (tid < NC * NC) {
        const int t = tid / NC;
        const int c = tid - t * NC;
        // wc[c][t] = (wei_confus[c][t] + FUS * cm[c][t]/col[t]) / (1+FUS)
        const float wc = (wei_confus[c * NC + t]
                          + FUS_F * sCmt[c * NC + t] * cinv[t]) * (1.0f / (1.0f + FUS_F));
        partv = sAt[tid] * wc;
    }
    #pragma unroll
    for (int o = 32; o > 0; o >>= 1) partv += __shfl_down(partv, o, 64);
    if ((tid & 63) == 0) red[tid >> 6] = partv;
    __syncthreads();

    if (tid == 0) {
        const float tot = red[0] + red[1] + red[2] + red[3];
        float ce = 0.0f, bls = 0.0f;
        for (int p = 0; p < NPART; ++p) { ce += gsums[p * 2 + 0]; bls += gsums[p * 2 + 1]; }
        out[0] = (bls * (1.0f / NC) - tot * (1.0f / NC) + DELTA_F * ce) * (1.0f / (float)NPIX);
    }
}

extern "C" void kernel_launch(void* const* d_in, const int* in_sizes, int n_in,
                              void* d_out, int out_size, void* d_ws, size_t ws_size,
                              hipStream_t stream) {
    const float* y_pred     = (const float*)d_in[0];
    const float* wei_confus = (const float*)d_in[1];
    const float* weight     = (const float*)d_in[2];
    const int*   y_true     = (const int*)d_in[3];
    const int*   backlabel  = (const int*)d_in[4];

    float*    gA    = (float*)d_ws;
    unsigned* gcm   = (unsigned*)((char*)d_ws + NPART * 196 * 4);
    float*    gsums = (float*)((char*)d_ws + 2 * NPART * 196 * 4);

    hipMemsetAsync(d_ws, 0, (2 * NPART * 196 + NPART * 2) * 4, stream);

    main_pass<<<NBLOCKS, 256, 0, stream>>>(y_pred, weight, y_true, backlabel, gA, gcm, gsums);
    finalize_pass<<<1, 256, 0, stream>>>(gA, gcm, gsums, wei_confus, (float*)d_out);
}

// Round 4
// 266.544 us; speedup vs baseline: 2.5487x; 1.1402x over previous
//
#include <hip/hip_runtime.h>

#define HW (512*512)           // 2^18
#define NB 8
#define NC 14
#define NPIX (NB*HW)
#define DELTA_F 0.7f
#define FUS_F 0.01f
#define NWAVES 4
#define NPART 8
#define NBLOCKS 2048
#define NTHREADS (NBLOCKS*256)
#define ITERS (NPIX/NTHREADS)  // 4

// ws layout (bytes):
//   [0    .. 6272)  gcm : uint  [NPART][196]
//   [6272 .. 6336)  gsc : float [NPART][2]   (ce, bl)
//   [6336 .. 6368)  gpj : float [NPART]
//   [6368 .. 7152)  gwc : float [196]        (wcT[t][c], written by fa)

#define REPEAT13(OP) OP(1) OP(2) OP(3) OP(4) OP(5) OP(6) OP(7) OP(8) OP(9) OP(10) OP(11) OP(12) OP(13)
#define REPEAT14(OP) OP(0) REPEAT13(OP)

// ---- k1: confusion matrix + CE + bl sums. ONE LDS atomic per pixel. ----
__global__ __launch_bounds__(256, 8) void k1_cm_ce(
    const float* __restrict__ y_pred, const float* __restrict__ weight,
    const int* __restrict__ y_true, const int* __restrict__ backlabel,
    unsigned* __restrict__ gcm, float* __restrict__ gsc)
{
    __shared__ unsigned sCM[NWAVES][NC * NC];
    __shared__ float sW[NC];
    __shared__ float sCe[NWAVES], sBl[NWAVES];

    const int tid = threadIdx.x;
    const int wv  = tid >> 6;
    for (int j = tid; j < NWAVES * NC * NC; j += 256) (&sCM[0][0])[j] = 0u;
    if (tid < NC) sW[tid] = weight[tid];
    __syncthreads();

    float ceAcc = 0.0f, blAcc = 0.0f;
    const int gid = blockIdx.x * 256 + tid;

    #pragma unroll 1
    for (int i = 0; i < ITERS; ++i) {
        const int q  = gid + i * NTHREADS;
        const int b  = q >> 18;
        const int hw = q & (HW - 1);
        const float* px = y_pred + (((size_t)b * NC) << 18) + hw;

        #define LOADC(c) float x##c = px[(size_t)(c) << 18];
        REPEAT14(LOADC)
        #undef LOADC

        int t = y_true[q];
        t = (t < 0) ? 0 : ((t >= NC) ? (NC - 1) : t);
        const int bb = backlabel[q];
        const float bl = (bb == 0) ? 0.4f : (float)bb;

        // max + argmax (first occurrence via strict >)
        float m = x0; int am = 0;
        #define AMAX(c) if (x##c > m) { m = x##c; am = (c); }
        REPEAT13(AMAX)
        #undef AMAX

        // x[t] select
        float xt = x0;
        #define SELT(c) xt = (t == (c)) ? x##c : xt;
        REPEAT13(SELT)
        #undef SELT

        // sum of exp only (no per-channel e kept)
        float s = 0.0f;
        #define EXPC(c) s += __expf(x##c - m);
        REPEAT14(EXPC)
        #undef EXPC

        ceAcc += sW[t] * (m + __logf(s) - xt) * bl;
        blAcc += bl;

        atomicAdd(&sCM[wv][t * NC + am], 1u);   // ~196 spread addrs: near conflict-free
    }

    #pragma unroll
    for (int o = 32; o > 0; o >>= 1) {
        ceAcc += __shfl_down(ceAcc, o, 64);
        blAcc += __shfl_down(blAcc, o, 64);
    }
    if ((tid & 63) == 0) { sCe[wv] = ceAcc; sBl[wv] = blAcc; }
    __syncthreads();

    const int part = blockIdx.x & (NPART - 1);
    if (tid < NC * NC) {
        const unsigned cmv = sCM[0][tid] + sCM[1][tid] + sCM[2][tid] + sCM[3][tid];
        if (cmv) atomicAdd(&gcm[part * NC * NC + tid], cmv);
    }
    if (tid == 0) unsafeAtomicAdd(&gsc[part * 2 + 0], sCe[0] + sCe[1] + sCe[2] + sCe[3]);
    if (tid == 1) unsafeAtomicAdd(&gsc[part * 2 + 1], sBl[0] + sBl[1] + sBl[2] + sBl[3]);
}

// ---- fa: build wcT[t][c] from cm ----
__global__ __launch_bounds__(256) void fa_build_wc(
    const unsigned* __restrict__ gcm, const float* __restrict__ wei_confus,
    float* __restrict__ gwc)
{
    __shared__ float sCmt[NC * NC];
    __shared__ float cinv[NC];
    const int tid = threadIdx.x;

    if (tid < NC * NC) {
        unsigned cmv = 0u;
        for (int p = 0; p < NPART; ++p) cmv += gcm[p * NC * NC + tid];
        sCmt[tid] = (float)cmv;
    }
    __syncthreads();
    if (tid < NC) {
        float col = 0.0f;
        for (int r = 0; r < NC; ++r) col += sCmt[r * NC + tid];
        cinv[tid] = (col == 0.0f) ? 1.0f : (1.0f / col);
    }
    __syncthreads();
    if (tid < NC * NC) {
        const int t = tid / NC;       // target class (column of wc)
        const int c = tid - t * NC;   // prob channel (row of wc)
        gwc[t * NC + c] = (wei_confus[c * NC + t]
                           + FUS_F * sCmt[c * NC + t] * cinv[t]) * (1.0f / (1.0f + FUS_F));
    }
}

// ---- k2: projection sum. Pure streaming + LDS reads; 1 global atomic/block. ----
__global__ __launch_bounds__(256, 8) void k2_proj(
    const float* __restrict__ y_pred, const float* __restrict__ gwc,
    const int* __restrict__ y_true, const int* __restrict__ backlabel,
    float* __restrict__ gpj)
{
    __shared__ float sWC[NC * NC];
    __shared__ float sPj[NWAVES];
    const int tid = threadIdx.x;
    const int wv  = tid >> 6;
    if (tid < NC * NC) sWC[tid] = gwc[tid];
    __syncthreads();

    float pjAcc = 0.0f;
    const int gid = blockIdx.x * 256 + tid;

    #pragma unroll 1
    for (int i = 0; i < ITERS; ++i) {
        const int q  = gid + i * NTHREADS;
        const int b  = q >> 18;
        const int hw = q & (HW - 1);
        const float* px = y_pred + (((size_t)b * NC) << 18) + hw;

        #define LOADC(c) float x##c = px[(size_t)(c) << 18];
        REPEAT14(LOADC)
        #undef LOADC

        int t = y_true[q];
        t = (t < 0) ? 0 : ((t >= NC) ? (NC - 1) : t);
        const int bb = backlabel[q];
        const float bl = (bb == 0) ? 0.4f : (float)bb;

        float m = x0;
        #define MAXC(c) m = fmaxf(m, x##c);
        REPEAT13(MAXC)
        #undef MAXC

        const float* wrow = &sWC[t * NC];
        float s = 0.0f, d = 0.0f;
        #define PROJC(c) { const float e = __expf(x##c - m); s += e; d = fmaf(e, wrow[(c)], d); }
        REPEAT14(PROJC)
        #undef PROJC

        pjAcc += bl * d / s;
    }

    #pragma unroll
    for (int o = 32; o > 0; o >>= 1) pjAcc += __shfl_down(pjAcc, o, 64);
    if ((tid & 63) == 0) sPj[wv] = pjAcc;
    __syncthreads();
    if (tid == 0)
        unsafeAtomicAdd(&gpj[blockIdx.x & (NPART - 1)], sPj[0] + sPj[1] + sPj[2] + sPj[3]);
}

// ---- fb: combine ----
__global__ void fb_combine(const float* __restrict__ gsc, const float* __restrict__ gpj,
                           float* __restrict__ out)
{
    if (threadIdx.x == 0) {
        float ce = 0.0f, bls = 0.0f, pj = 0.0f;
        for (int p = 0; p < NPART; ++p) {
            ce += gsc[p * 2 + 0]; bls += gsc[p * 2 + 1]; pj += gpj[p];
        }
        out[0] = ((bls - pj) * (1.0f / NC) + DELTA_F * ce) * (1.0f / (float)NPIX);
    }
}

extern "C" void kernel_launch(void* const* d_in, const int* in_sizes, int n_in,
                              void* d_out, int out_size, void* d_ws, size_t ws_size,
                              hipStream_t stream) {
    const float* y_pred     = (const float*)d_in[0];
    const float* wei_confus = (const float*)d_in[1];
    const float* weight     = (const float*)d_in[2];
    const int*   y_true     = (const int*)d_in[3];
    const int*   backlabel  = (const int*)d_in[4];

    unsigned* gcm = (unsigned*)d_ws;
    float*    gsc = (float*)((char*)d_ws + 6272);
    float*    gpj = (float*)((char*)d_ws + 6336);
    float*    gwc = (float*)((char*)d_ws + 6368);

    hipMemsetAsync(d_ws, 0, 6368, stream);

    k1_cm_ce<<<NBLOCKS, 256, 0, stream>>>(y_pred, weight, y_true, backlabel, gcm, gsc);
    fa_build_wc<<<1, 256, 0, stream>>>(gcm, wei_confus, gwc);
    k2_proj<<<NBLOCKS, 256, 0, stream>>>(y_pred, gwc, y_true, backlabel, gpj);
    fb_combine<<<1, 64, 0, stream>>>(gsc, gpj, (float*)d_out);
}